// Round 7
// baseline (225.730 us; speedup 1.0000x reference)
//
#include <hip/hip_runtime.h>

// HistogramLoss: two [32,3,512,512] fp32 inputs, per-(B,C) 64-bin histogram
// over [0,1], row-normalized (row count exactly 2^18), L1 mean of diff.
//
// R12: R11's de-phase retried with a BIJECTIVE rotation. R11 failed
// because rot was per-wave: each wave's index set {i*256+tid} has its
// lane-window in low-8-bits [wv*64,wv*64+64); per-wave shifts made the
// windows overlap -> double/missed reads (absmax 4e-5). Fix:
//  (1) rot is per-BLOCK only, 1KB-aligned: rot = ((b*37)&127)<<6.
//      Block coverage = {k+rot mod 8192} = whole chunk. Exact.
//  (2) waves de-phase in TIME: wave wv visits its iterations in order
//      (i + 8*wv) & 31 — a permutation of its own visit order (index
//      set unchanged) -> 4 waves sit 8KB apart at any instant.
// Theory unchanged (untested until now): R5/R6/R7/R9/R10 all deliver
// 4 B/cy/CU across different consume pipes, memory paths, and guaranteed
// in-flight depth; all share chunk-aligned lockstep streams -> all
// concurrent requests carry identical low-17 address bits -> same
// channel subset -> GPU-wide channel convoy. R8's accidental scratch
// traffic (scattered addresses) hit 2.5 TB/s on this chip. De-phasing
// blocks across 1KB offsets breaks the convoy.
// Keeps R9 structure: ring-8, sched_barrier(0x7), launch_bounds(256,4),
// 8 planes, 128 elems/thread, capacity 255 -> exact (absmax 0).

#define HW        262144             // 512*512 = 2^18
#define ROWS      96                 // B*C per image
#define NBINS     64
#define BPR       8                  // blocks per row
#define CHUNK     (HW / BPR)         // 32768 elements per block (8192 f4)
#define THREADS   256
#define F4_ITERS  (CHUNK / 4 / THREADS)  // 32 float4 per thread -> 128 elems
#define NBLOCKS   (2 * ROWS * BPR)   // 1536
#define RING      8                  // float4 loads in flight per wave
#define F4MASK    8191               // f4 per chunk - 1

typedef unsigned long long u64;

// 4:2 carry-save compress four one-hot u64s into 8 bit-planes p0..p7.
// bit bb of pk = bit k of this thread's count for bin bb. Max count 128.
#define PROC4(v) do {                                                   \
    int b0 = min((int)((v).x * 64.0f), 63);                             \
    int b1 = min((int)((v).y * 64.0f), 63);                             \
    int b2 = min((int)((v).z * 64.0f), 63);                             \
    int b3 = min((int)((v).w * 64.0f), 63);                             \
    u64 m0 = 1ull << b0, m1 = 1ull << b1;                               \
    u64 m2 = 1ull << b2, m3 = 1ull << b3;                               \
    u64 s1 = m0 ^ m1, c1 = m0 & m1;                                     \
    u64 s2 = m2 ^ m3, c2 = m2 & m3;                                     \
    u64 S  = s1 ^ s2, C  = s1 & s2;                                     \
    u64 g0 = p0 & S;  p0 ^= S;                                          \
    u64 u  = c1 ^ c2, vv = c1 & c2;                                     \
    u64 s3 = u ^ C,   w  = u & C;                                       \
    u64 t3 = vv | w;                                                    \
    u64 t  = s3 ^ g0;                                                   \
    u64 g1 = (p1 & t) | (s3 & g0);  p1 ^= t;                            \
    u64 t2 = t3 ^ g1;                                                   \
    u64 g2 = (p2 & t2) | (t3 & g1); p2 ^= t2;                           \
    u64 g3 = p3 & g2; p3 ^= g2;                                         \
    u64 g4 = p4 & g3; p4 ^= g3;                                         \
    u64 g5 = p5 & g4; p5 ^= g4;                                         \
    u64 g6 = p6 & g5; p6 ^= g5;                                         \
    p7 ^= g6;                                                           \
} while (0)

// Index of stage (i+k) for this thread: wave-local time permutation
// ((i+k+8*wv)&31) picks which 256-f4 slab; +tid lane placement; +rot
// block de-phase; &F4MASK wraps within the chunk. Bijective per block.
#define IDX(ik) (((((ik) + woff) & 31) * THREADS + tr) & F4MASK)

// One pipeline stage: consume slot fk, then re-issue its load.
// sched_barrier(0x7): ALU/VALU/SALU may cross, VMEM pinned.
#define STAGE(fk, ik) do {                                              \
    PROC4(fk);                                                          \
    fk = qbase[IDX(ik)];                                                \
    __builtin_amdgcn_sched_barrier(0x7);                                \
} while (0)

__global__ __launch_bounds__(THREADS, 4)
void hist_kernel(const float* __restrict__ fake,
                 const float* __restrict__ real,
                 unsigned int* __restrict__ partial) {
    __shared__ unsigned int bhist[NBINS];

    const int tid  = threadIdx.x;
    const int lane = tid & 63;
    const int wv   = tid >> 6;

    if (tid < NBINS) bhist[tid] = 0u;
    __syncthreads();

    const int b     = blockIdx.x;          // 0 .. 1535
    const int chunk = b & (BPR - 1);
    const int rowg  = b >> 3;              // 0..191: img*ROWS + row
    const float* src = (rowg < ROWS) ? fake : real;
    const int row    = (rowg < ROWS) ? rowg : (rowg - ROWS);

    const float4* __restrict__ qbase =
        (const float4*)(src + (size_t)row * HW + (size_t)chunk * CHUNK);

    // Per-BLOCK de-phase, 1KB-aligned (wave loads stay 1KB-aligned).
    const int rot  = ((b * 37) & 127) << 6;   // multiples of 64 f4
    const int tr   = tid + rot;
    const int woff = wv << 3;                 // wave time-phase: 8 iters

    u64 p0 = 0, p1 = 0, p2 = 0, p3 = 0, p4 = 0, p5 = 0, p6 = 0, p7 = 0;

    // Prologue: fill the ring — 8 wave-loads in flight.
    float4 f0 = qbase[IDX(0)];
    float4 f1 = qbase[IDX(1)];
    float4 f2 = qbase[IDX(2)];
    float4 f3 = qbase[IDX(3)];
    float4 f4 = qbase[IDX(4)];
    float4 f5 = qbase[IDX(5)];
    float4 f6 = qbase[IDX(6)];
    float4 f7 = qbase[IDX(7)];
    __builtin_amdgcn_sched_barrier(0x7);

    // Steady state: every stage consumes one slot and refills it.
#pragma unroll 1
    for (int i = RING; i <= F4_ITERS - RING; i += RING) {
        STAGE(f0, i + 0);
        STAGE(f1, i + 1);
        STAGE(f2, i + 2);
        STAGE(f3, i + 3);
        STAGE(f4, i + 4);
        STAGE(f5, i + 5);
        STAGE(f6, i + 6);
        STAGE(f7, i + 7);
    }
    // Epilogue: drain the ring.
    PROC4(f0); PROC4(f1); PROC4(f2); PROC4(f3);
    PROC4(f4); PROC4(f5); PROC4(f6); PROC4(f7);

    // Flush: wave-sum per bin via ballot+popcount of each plane's bit.
    unsigned mycnt = 0;
#pragma unroll
    for (int bb = 0; bb < NBINS; ++bb) {
        unsigned ws =
              (unsigned)__popcll(__ballot((unsigned)((p0 >> bb) & 1ull)))
            + ((unsigned)__popcll(__ballot((unsigned)((p1 >> bb) & 1ull))) << 1)
            + ((unsigned)__popcll(__ballot((unsigned)((p2 >> bb) & 1ull))) << 2)
            + ((unsigned)__popcll(__ballot((unsigned)((p3 >> bb) & 1ull))) << 3)
            + ((unsigned)__popcll(__ballot((unsigned)((p4 >> bb) & 1ull))) << 4)
            + ((unsigned)__popcll(__ballot((unsigned)((p5 >> bb) & 1ull))) << 5)
            + ((unsigned)__popcll(__ballot((unsigned)((p6 >> bb) & 1ull))) << 6)
            + ((unsigned)__popcll(__ballot((unsigned)((p7 >> bb) & 1ull))) << 7);
        if (lane == bb) mycnt = ws;
    }
    // One LDS atomic per lane per wave for the entire kernel.
    atomicAdd(&bhist[lane], mycnt);
    __syncthreads();

    if (tid < NBINS)
        partial[(size_t)b * NBINS + tid] = bhist[tid];   // plain store
}

// Stage 1: 24 blocks x 256 threads; each thread owns one (row,bin) pair.
__global__ __launch_bounds__(256)
void loss1_kernel(const unsigned int* __restrict__ partial,
                  unsigned int* __restrict__ blocksum) {
    const int tid = threadIdx.x;
    const int g   = blockIdx.x * 256 + tid;   // 0..6143
    const int r   = g >> 6;
    const int bb  = g & 63;
    unsigned cf = 0, cr = 0;
#pragma unroll
    for (int c = 0; c < BPR; ++c) {
        cf += partial[((r * BPR + c) * NBINS) + bb];
        cr += partial[(((ROWS + r) * BPR + c) * NBINS) + bb];
    }
    int d = (int)cf - (int)cr;
    int a = (d < 0) ? -d : d;
#pragma unroll
    for (int off = 32; off > 0; off >>= 1)
        a += __shfl_down(a, off, 64);
    __shared__ int wsum[4];
    if ((tid & 63) == 0) wsum[tid >> 6] = a;
    __syncthreads();
    if (tid == 0)
        blocksum[blockIdx.x] = (unsigned)(wsum[0] + wsum[1] + wsum[2] + wsum[3]);
}

// Stage 2: one wave folds the 24 block sums.
__global__ __launch_bounds__(64)
void loss2_kernel(const unsigned int* __restrict__ blocksum,
                  float* __restrict__ out) {
    const int lane = threadIdx.x;
    int a = (lane < 24) ? (int)blocksum[lane] : 0;
#pragma unroll
    for (int off = 32; off > 0; off >>= 1)
        a += __shfl_down(a, off, 64);
    if (lane == 0)
        out[0] = (float)((double)a / (262144.0 * 6144.0));
}

extern "C" void kernel_launch(void* const* d_in, const int* in_sizes, int n_in,
                              void* d_out, int out_size, void* d_ws, size_t ws_size,
                              hipStream_t stream) {
    const float* fake = (const float*)d_in[0];
    const float* real = (const float*)d_in[1];
    unsigned int* partial  = (unsigned int*)d_ws;            // 1536*64 u32 = 393216 B
    unsigned int* blocksum = partial + NBLOCKS * NBINS;      // 24 u32
    float* out = (float*)d_out;

    hist_kernel<<<NBLOCKS, THREADS, 0, stream>>>(fake, real, partial);
    loss1_kernel<<<24, 256, 0, stream>>>(partial, blocksum);
    loss2_kernel<<<1, 64, 0, stream>>>(blocksum, out);
}